// Round 17
// baseline (131.080 us; speedup 1.0000x reference)
//
#include <hip/hip_runtime.h>

typedef short bf16x8 __attribute__((ext_vector_type(8)));
typedef float f32x16 __attribute__((ext_vector_type(16)));

#define BIG_F 1e10f
constexpr int B = 16;
constexpr int N = 4096;
constexpr int COLS = 512;           // cols per block (L1-resident table slice)
constexpr int NCB = N / COLS;       // 8
constexpr int JOBS = 4;             // 128-row jobs per block
constexpr int SUBROWS = 512;        // rows per block
constexpr int NSUB = N / SUBROWS;   // 8
// per-direction partials: [B][NCB][2 ssets][N]
constexpr size_t PARTSZ = (size_t)B * NCB * 2 * N;   // 4 MB of floats

// truncating bf16 hi/lo split: v ~= hi + lo
__device__ __forceinline__ void split(float v, unsigned& h, unsigned& l) {
    unsigned hb = __float_as_uint(v) & 0xFFFF0000u;
    h = hb >> 16;
    float r = v - __uint_as_float(hb);
    l = __float_as_uint(r) >> 16;
}

__device__ __forceinline__ float4 min4(float4 a, float4 b) {
    return make_float4(fminf(a.x, b.x), fminf(a.y, b.y),
                       fminf(a.z, b.z), fminf(a.w, b.w));
}

// VALU-pipe cross-lane min via DPP (no ds-op). Validated exact (R8-R15).
#define DPP_MIN(v, ctrl)                                                      \
    v = fminf(v, __int_as_float(__builtin_amdgcn_update_dpp(                  \
            __float_as_int(v), __float_as_int(v), (ctrl), 0xF, 0xF, false)))

// Fragment styles (bit-identical across both MFMA operand roles — R14):
// ROWstyle(v, s=|v|^2+madd): k = [ah0..2,ah0..2,al0..2, sh,sl,1,1]  (a=-2v)
// COLstyle(v, s=|v|^2+madd): k = [vh0..2,vl0..2,vh0..2,vl0..2, 1,1, sh,sl]
__device__ __forceinline__ void rowstyle(float v0, float v1, float v2,
                                         float madd, uint4& w0, uint4& w1) {
    float s = fmaf(v2, v2, fmaf(v1, v1, v0 * v0)) + madd;
    unsigned h0, l0, h1, l1, h2, l2, sh, sl;
    split(-2.0f * v0, h0, l0);
    split(-2.0f * v1, h1, l1);
    split(-2.0f * v2, h2, l2);
    split(s, sh, sl);
    w0 = make_uint4(h0 | (h1 << 16), h2 | (h0 << 16), h1 | (h2 << 16), l0 | (l1 << 16));
    w1 = make_uint4(l2 | (l0 << 16), l1 | (l2 << 16), sh | (sl << 16), 0x3F803F80u);
}
__device__ __forceinline__ void colstyle(float v0, float v1, float v2,
                                         float madd, uint4& w0, uint4& w1) {
    float s = fmaf(v2, v2, fmaf(v1, v1, v0 * v0)) + madd;
    unsigned h0, l0, h1, l1, h2, l2, sh, sl;
    split(v0, h0, l0);
    split(v1, h1, l1);
    split(v2, h2, l2);
    split(s, sh, sl);
    unsigned u0 = h0 | (h1 << 16), u1 = h2 | (l0 << 16), u2 = l1 | (l2 << 16);
    w0 = make_uint4(u0, u1, u2, u0);
    w1 = make_uint4(u1, u2, 0x3F803F80u, sh | (sl << 16));
}

// Pack each point ONCE into two global fragment tables (validated R5/R15):
// Txrow = rowstyle(x) — A-side of dir0, B-side of dir1
// Tycol = colstyle(y) — B-side of dir0, A-side of dir1
__global__ __launch_bounds__(256) void pack_kernel(
    const float* __restrict__ x, const float* __restrict__ y,
    const int* __restrict__ mask,
    uint4* __restrict__ Txrow, uint4* __restrict__ Tycol,
    float* __restrict__ out)
{
    const int idx = blockIdx.x * 256 + threadIdx.x;   // 65536 = 16*4096
    if (idx == 0) out[0] = 0.0f;                      // finalize accumulates later
    const int b  = idx >> 12;
    const int pt = idx & (N - 1);
    const float* xb = x + (size_t)b * 3 * N;
    const float* yb = y + (size_t)b * 3 * N;
    const float madd = mask[b * N + pt] ? 0.0f : BIG_F;
    uint4 w0, w1;
    rowstyle(xb[pt], xb[N + pt], xb[2 * N + pt], madd, w0, w1);
    Txrow[(size_t)(b * 2 + 0) * N + pt] = w0;
    Txrow[(size_t)(b * 2 + 1) * N + pt] = w1;
    colstyle(yb[pt], yb[N + pt], yb[2 * N + pt], madd, w0, w1);
    Tycol[(size_t)(b * 2 + 0) * N + pt] = w0;
    Tycol[(size_t)(b * 2 + 1) * N + pt] = w1;
}

// R16/R17: LDS-free, barrier-free, max-occupancy chamfer.
// Session finding: time tracks inner-loop VALU instr/tile (R13 fused 17 ->
// 41.5us/vol; R15 lean 8 -> 24us/vol) and occupancy never exceeded 6 w/SIMD
// because every design spent LDS on staging. Here: B fragments read DIRECTLY
// from the pre-packed global table (block's 32KB slice is L1-resident after
// first touch; tables are 4MB, L2-resident). Zero LDS, zero barriers, ILP-1
// body (~46 live regs: C 16 + rm 16 + afr 4 + bf 4 + addr) at (256,8) ->
// 8 waves/SIMD, grid 2048 = ONE full-occupancy generation.
// Tripwires: WRITE_SIZE ~8 MB (else spill); FETCH_SIZE <~100 MB (else the
// L1-residency assumption is wrong -> restore LDS staging at (256,6)).
__global__ __launch_bounds__(256, 8) void chamfer_mfma(
    const uint4* __restrict__ Txrow, const uint4* __restrict__ Tycol,
    float* __restrict__ part)      // [2][B][NCB][2][N]: dir0=mins2, dir1=mins1
{
    const int blk  = blockIdx.x;    // 0..2047
    const int dir  = blk & 1;
    const int rest = blk >> 1;
    const int b    = rest >> 6;
    const int cb   = (rest >> 3) & 7;
    const int sub  = rest & 7;
    const int t    = threadIdx.x;

    const uint4* rowT = dir ? Tycol : Txrow;   // A-frag table (per-lane rows)
    const uint4* colT = dir ? Txrow : Tycol;   // B-frag table (read per iter)

    const int w    = t >> 6;    // wave 0..3
    const int L    = t & 63;
    const int half = L >> 5;    // k-half 0/1
    const int lc   = L & 31;

    // per-lane B base: khalf table, this block's 512-col slice
    const uint4* Bg = colT + (size_t)(b * 2 + half) * N + cb * COLS + lc;
    const uint4* Ag = rowT + (size_t)(b * 2 + half) * N + sub * SUBROWS + w * 32 + lc;

    const f32x16 z16 = {0.f,0.f,0.f,0.f,0.f,0.f,0.f,0.f,
                        0.f,0.f,0.f,0.f,0.f,0.f,0.f,0.f};
    float* pbase = part + (size_t)dir * PARTSZ;

#pragma unroll 1
    for (int jj = 0; jj < JOBS; ++jj) {
        const int rowbase = sub * SUBROWS + jj * 128;
        // A fragment: one 16B global load from the pre-packed table
        uint4 av = Ag[jj * 128];
        bf16x8 afr = *(bf16x8*)&av;

        float rm[16];
#pragma unroll
        for (int r = 0; r < 16; ++r) rm[r] = 1e30f;

#pragma unroll 1
        for (int p = 0; p < 16; ++p) {         // 16 col-chunks of 32 = 512 cols
            uint4 bv = Bg[p * 32];             // L1-hot after first pass
            bf16x8 bf = *(bf16x8*)&bv;
            f32x16 C = __builtin_amdgcn_mfma_f32_32x32x16_bf16(afr, bf, z16, 0, 0, 0);
            // C[r]: row = rowbase + w*32 + (r&3)+8*(r>>2)+4*half, col = p*32+lc
#pragma unroll
            for (int r = 0; r < 16; ++r) rm[r] = fminf(rm[r], C[r]);
        }

        // ---- row-min over each 16-lane group, entirely on the VALU pipe ----
#pragma unroll
        for (int r = 0; r < 16; ++r) {
            DPP_MIN(rm[r], 0xB1);    // quad_perm xor1
            DPP_MIN(rm[r], 0x4E);    // quad_perm xor2
            DPP_MIN(rm[r], 0x124);   // row_ror:4
            DPP_MIN(rm[r], 0x128);   // row_ror:8
        }
        if ((lc & 15) == 0) {        // lanes 0,16,32,48: (half, col-subset)
            int sset = lc >> 4;      // min over cols with (c&31) in sset*16+[0,15]
            float* rp = pbase + (((size_t)(b * NCB + cb)) * 2 + sset) * N
                      + rowbase + w * 32 + half * 4;
            *(float4*)(rp +  0) = make_float4(rm[0],  rm[1],  rm[2],  rm[3]);
            *(float4*)(rp +  8) = make_float4(rm[4],  rm[5],  rm[6],  rm[7]);
            *(float4*)(rp + 16) = make_float4(rm[8],  rm[9],  rm[10], rm[11]);
            *(float4*)(rp + 24) = make_float4(rm[12], rm[13], rm[14], rm[15]);
        }
    }
}

__global__ __launch_bounds__(256) void finalize_kernel(
    const int* __restrict__ mask,
    const float* __restrict__ part,
    float* __restrict__ out)
{
    const int b = blockIdx.x & 15;
    const int q = blockIdx.x >> 4;   // quarter 0..3
    const int t = threadIdx.x;
    const int* mrow = mask + b * N;

    int cnt = 0;
    for (int i = t; i < N / 4; i += 256) {
        int4 mk = ((const int4*)mrow)[i];
        cnt += mk.x + mk.y + mk.z + mk.w;
    }

    const int p0 = q * 1024 + t * 4;
    const float* d0 = part + (size_t)b * NCB * 2 * N + p0;            // mins2
    const float* d1 = part + PARTSZ + (size_t)b * NCB * 2 * N + p0;   // mins1

    float4 rn = *(const float4*)d0;
    float4 mn = *(const float4*)d1;
#pragma unroll 8
    for (int pb = 1; pb < NCB * 2; ++pb) {
        rn = min4(rn, *(const float4*)(d0 + (size_t)pb * N));
        mn = min4(mn, *(const float4*)(d1 + (size_t)pb * N));
    }
    int4 mk = *(const int4*)(mrow + p0);
    float s = (mk.x ? (mn.x + rn.x) : 0.f) + (mk.y ? (mn.y + rn.y) : 0.f)
            + (mk.z ? (mn.z + rn.z) : 0.f) + (mk.w ? (mn.w + rn.w) : 0.f);

    for (int off = 32; off > 0; off >>= 1) {
        s   += __shfl_down(s, off);
        cnt += __shfl_down(cnt, off);
    }
    __shared__ float rs[4];
    __shared__ int   rc[4];
    const int wv = t >> 6;
    if ((t & 63) == 0) { rs[wv] = s; rc[wv] = cnt; }
    __syncthreads();
    if (t == 0) {
        float S = rs[0] + rs[1] + rs[2] + rs[3];
        float C = (float)(rc[0] + rc[1] + rc[2] + rc[3]);
        atomicAdd(out, (S / C) * (1.0f / 16.0f));
    }
}

extern "C" void kernel_launch(void* const* d_in, const int* in_sizes, int n_in,
                              void* d_out, int out_size, void* d_ws, size_t ws_size,
                              hipStream_t stream) {
    const float* x    = (const float*)d_in[0];
    const float* y    = (const float*)d_in[1];
    const int*   mask = (const int*)d_in[2];

    uint4* Txrow = (uint4*)d_ws;                          // B*2*N uint4 = 2 MB
    uint4* Tycol = Txrow + (size_t)B * 2 * N;             // 2 MB
    float* part  = (float*)(Tycol + (size_t)B * 2 * N);   // 2*PARTSZ = 8 MB

    pack_kernel<<<dim3(B * N / 256), 256, 0, stream>>>(
        x, y, mask, Txrow, Tycol, (float*)d_out);
    chamfer_mfma<<<dim3(2 * B * NCB * NSUB), 256, 0, stream>>>(
        Txrow, Tycol, part);
    finalize_kernel<<<dim3(64), 256, 0, stream>>>(
        mask, part, (float*)d_out);
}

// Round 19
// 87.677 us; speedup vs baseline: 1.4950x; 1.4950x over previous
//
#include <hip/hip_runtime.h>

typedef short bf16x8 __attribute__((ext_vector_type(8)));
typedef float f32x16 __attribute__((ext_vector_type(16)));

#define BIG_F 1e10f
constexpr int B = 16;
constexpr int N = 4096;
constexpr int COLS = 512;           // y-cols per block
constexpr int NCB = N / COLS;       // 8 col-blocks
constexpr int JOBS = 4;             // 128-row jobs per block
constexpr int SUBROWS = 128 * JOBS; // 512 rows per block
constexpr int NSB = N / SUBROWS;    // 8 row-superblocks

// truncating bf16 hi/lo split: v ~= hi + lo
__device__ __forceinline__ void split(float v, unsigned& h, unsigned& l) {
    unsigned hb = __float_as_uint(v) & 0xFFFF0000u;
    h = hb >> 16;
    float r = v - __uint_as_float(hb);
    l = __float_as_uint(r) >> 16;
}

__device__ __forceinline__ float min3f(float a, float b, float c) {
    return fminf(fminf(a, b), c);   // fuses to v_min3_f32
}

__device__ __forceinline__ float vmin16(f32x16 C) {
    float u0 = min3f(C[0], C[1], C[2]);
    float u1 = min3f(C[3], C[4], C[5]);
    float u2 = min3f(C[6], C[7], C[8]);
    float u3 = min3f(C[9], C[10], C[11]);
    float u4 = min3f(C[12], C[13], C[14]);
    return min3f(min3f(u0, u1, u2), fminf(u3, u4), C[15]);
}

__device__ __forceinline__ float4 min4(float4 a, float4 b) {
    return make_float4(fminf(a.x, b.x), fminf(a.y, b.y),
                       fminf(a.z, b.z), fminf(a.w, b.w));
}

// VALU-pipe cross-lane min via DPP (no ds-op). Validated exact (R8-R17).
#define DPP_MIN(v, ctrl)                                                      \
    v = fminf(v, __int_as_float(__builtin_amdgcn_update_dpp(                  \
            __float_as_int(v), __float_as_int(v), (ctrl), 0xF, 0xF, false)))

// P[n,m] = xx[n] + yy[m] - 2 x_n . y_m (+BIG masked) via mfma_f32_32x32x16_bf16:
//   A_k(n) = [ah0..2, ah0..2, al0..2, al0..2, xxh, xxl, 1, 1]  (ah+al = -2x)
//   B_k(m) = [yh0..2, yl0..2, yh0..2, yl0..2, 1, 1, qh, ql]    (qh+ql = yy)
// R18/R19 = R11 body (fused 1x-volume, 4 jobs/block, thread-owned LDS col-min
// rmw, DPP row-reduce, 2 barriers) with __launch_bounds__(256,5).
// Register-budget map from 18 rounds:
//   <=64-reg budget  -> compiler AGPR-izes acc+rm, 4x VALU (R17: 136 instr/iter)
//   128-budget + fat body -> scratch spill collapse (R3/R8)
//   ~102-170 + lean body  -> clean codegen (R11/R13)
// (256,5): budget 102, live ~60-70, LDS 32KB caps at 5 blocks/CU = matched.
// Tripwires: chamfer VGPR <= 50 -> AGPR-poisoned; WRITE_SIZE >> 6MB -> spill.
__global__ __launch_bounds__(256, 5) void chamfer_mfma(
    const float* __restrict__ x, const float* __restrict__ y,
    const int* __restrict__ mask,
    float* __restrict__ rowpart,   // [B][NCB][2][N] row-min partials (sset slabs)
    float* __restrict__ colpart,   // [B][NSB][N]    col-min partials (512 rows)
    float* __restrict__ out)
{
    const int blk = blockIdx.x;     // 0..1023
    const int b   = blk >> 6;
    const int cb  = (blk >> 3) & 7;
    const int sub = blk & 7;
    const int t   = threadIdx.x;

    __shared__ __align__(16) unsigned short Bpack[2][COLS][8];  // 16 KB
    __shared__ float colbuf[8][COLS];                           // 16 KB

    if (blk == 0 && t == 0) out[0] = 0.0f;   // finalize is the next dispatch

    const float* xb = x + (size_t)b * 3 * N;
    const float* yb = y + (size_t)b * 3 * N;
    const int*   mb = mask + b * N;

    // ---- pack this block's 512-col B slice (2 points/thread) ----
#pragma unroll
    for (int i = 0; i < 2; ++i) {
        int c = t + i * 256;
        int m = cb * COLS + c;
        float y0 = yb[m], y1 = yb[N + m], y2 = yb[2 * N + m];
        float madd = mb[m] ? 0.0f : BIG_F;
        float yy = fmaf(y2, y2, fmaf(y1, y1, y0 * y0)) + madd;
        unsigned h0, l0, h1, l1, h2, l2, qh, ql;
        split(y0, h0, l0);
        split(y1, h1, l1);
        split(y2, h2, l2);
        split(yy, qh, ql);
        unsigned u0 = h0 | (h1 << 16);
        unsigned u1 = h2 | (l0 << 16);
        unsigned u2 = l1 | (l2 << 16);
        uint4 w0 = { u0, u1, u2, u0 };
        uint4 w1 = { u1, u2, 0x3F803F80u, qh | (ql << 16) };
        *(uint4*)&Bpack[0][c][0] = w0;
        *(uint4*)&Bpack[1][c][0] = w1;
    }

    const int w    = t >> 6;    // wave 0..3, rows w*32..w*32+31 within a job
    const int L    = t & 63;
    const int half = L >> 5;    // k-half 0/1
    const int lc   = L & 31;

    __syncthreads();

    const unsigned short* Bb = &Bpack[half][lc][0];  // +p*512 shorts = col p*64+lc
    float* cacc0 = &colbuf[w * 2 + half][lc];        // thread-owned col-min slots

    const f32x16 z16 = {0.f,0.f,0.f,0.f,0.f,0.f,0.f,0.f,
                        0.f,0.f,0.f,0.f,0.f,0.f,0.f,0.f};

#pragma unroll 1
    for (int jj = 0; jj < JOBS; ++jj) {
        // ---- A fragment built in-register for this job's row ----
        bf16x8 afr;
        {
            int n = sub * SUBROWS + jj * 128 + w * 32 + lc;
            float x0 = xb[n], x1 = xb[N + n], x2 = xb[2 * N + n];
            float madd = mb[n] ? 0.0f : BIG_F;
            float xx = fmaf(x2, x2, fmaf(x1, x1, x0 * x0)) + madd;
            unsigned h0, l0, h1, l1, h2, l2, xh, xl;
            split(-2.0f * x0, h0, l0);
            split(-2.0f * x1, h1, l1);
            split(-2.0f * x2, h2, l2);
            split(xx, xh, xl);
            uint4 wa;
            wa.x = half ? (l2 | (l0 << 16)) : (h0 | (h1 << 16));
            wa.y = half ? (l1 | (l2 << 16)) : (h2 | (h0 << 16));
            wa.z = half ? (xh | (xl << 16)) : (h1 | (h2 << 16));
            wa.w = half ? 0x3F803F80u       : (l0 | (l1 << 16));
            afr = *(bf16x8*)&wa;
        }

        float rm[16];
#pragma unroll
        for (int r = 0; r < 16; ++r) rm[r] = 1e30f;

        bf16x8 nb0 = *(const bf16x8*)(Bb);
        bf16x8 nb1 = *(const bf16x8*)(Bb + 256);

#pragma unroll 1
        for (int p = 0; p < 8; ++p) {          // 8 col-pairs of 32 = 512 cols
            bf16x8 bf0 = nb0, bf1 = nb1;
            int pn = (p + 1) & 7;              // p=7 harmlessly re-reads p=0
            nb0 = *(const bf16x8*)(Bb + pn * 512);
            nb1 = *(const bf16x8*)(Bb + pn * 512 + 256);

            f32x16 C0 = __builtin_amdgcn_mfma_f32_32x32x16_bf16(afr, bf0, z16, 0, 0, 0);
            f32x16 C1 = __builtin_amdgcn_mfma_f32_32x32x16_bf16(afr, bf1, z16, 0, 0, 0);
            // C[r]: row = w*32 + (r&3)+8*(r>>2)+4*half, col = p*64(+32)+lc
#pragma unroll
            for (int r = 0; r < 16; ++r) rm[r] = min3f(rm[r], C0[r], C1[r]);
            // col-min accumulation in thread-owned LDS slots (rmw, race-free)
            float v0 = vmin16(C0), v1 = vmin16(C1);
            if (jj == 0) {
                cacc0[p * 64]      = v0;
                cacc0[p * 64 + 32] = v1;
            } else {
                cacc0[p * 64]      = fminf(cacc0[p * 64],      v0);
                cacc0[p * 64 + 32] = fminf(cacc0[p * 64 + 32], v1);
            }
        }

        // ---- row-min over each 16-lane group, entirely on the VALU pipe ----
#pragma unroll
        for (int r = 0; r < 16; ++r) {
            DPP_MIN(rm[r], 0xB1);    // quad_perm {1,0,3,2}  = xor1
            DPP_MIN(rm[r], 0x4E);    // quad_perm {2,3,0,1}  = xor2
            DPP_MIN(rm[r], 0x124);   // row_ror:4
            DPP_MIN(rm[r], 0x128);   // row_ror:8
        }
        if ((lc & 15) == 0) {        // lanes 0,16,32,48: (half, col-subset)
            int sset = lc >> 4;
            float* rp = rowpart + (((size_t)(b * NCB + cb)) * 2 + sset) * N
                      + sub * SUBROWS + jj * 128 + w * 32 + half * 4;
            *(float4*)(rp +  0) = make_float4(rm[0],  rm[1],  rm[2],  rm[3]);
            *(float4*)(rp +  8) = make_float4(rm[4],  rm[5],  rm[6],  rm[7]);
            *(float4*)(rp + 16) = make_float4(rm[8],  rm[9],  rm[10], rm[11]);
            *(float4*)(rp + 24) = make_float4(rm[12], rm[13], rm[14], rm[15]);
        }
    }

    __syncthreads();
    if (t < 128) {                   // combine 8 (wave,half) slabs, float4-wide
        const float4* cb4 = (const float4*)&colbuf[0][0];
        float4 v = cb4[t];
#pragma unroll
        for (int s = 1; s < 8; ++s) v = min4(v, cb4[s * 128 + t]);
        *(float4*)(colpart + ((size_t)b * NSB + sub) * N + cb * COLS + t * 4) = v;
    }
}

__global__ __launch_bounds__(256) void finalize_kernel(
    const int* __restrict__ mask,
    const float* __restrict__ rowpart, const float* __restrict__ colpart,
    float* __restrict__ out)
{
    const int b = blockIdx.x & 15;
    const int q = blockIdx.x >> 4;   // quarter 0..3
    const int t = threadIdx.x;
    const int* mrow = mask + b * N;

    int cnt = 0;
    for (int i = t; i < N / 4; i += 256) {
        int4 mk = ((const int4*)mrow)[i];
        cnt += mk.x + mk.y + mk.z + mk.w;
    }

    const int p0 = q * 1024 + t * 4;
    const float* cp = colpart + (size_t)b * NSB * N + p0;      // 8 slabs
    const float* rp = rowpart + (size_t)b * NCB * 2 * N + p0;  // 16 slabs

    float4 mn = *(const float4*)cp;
    float4 rn = *(const float4*)rp;
#pragma unroll 8
    for (int pb = 1; pb < NCB * 2; ++pb) {
        rn = min4(rn, *(const float4*)(rp + (size_t)pb * N));
        if (pb < NSB)
            mn = min4(mn, *(const float4*)(cp + (size_t)pb * N));
    }
    int4 mk = *(const int4*)(mrow + p0);
    float s = (mk.x ? (mn.x + rn.x) : 0.f) + (mk.y ? (mn.y + rn.y) : 0.f)
            + (mk.z ? (mn.z + rn.z) : 0.f) + (mk.w ? (mn.w + rn.w) : 0.f);

    for (int off = 32; off > 0; off >>= 1) {
        s   += __shfl_down(s, off);
        cnt += __shfl_down(cnt, off);
    }
    __shared__ float rs[4];
    __shared__ int   rc[4];
    const int wv = t >> 6;
    if ((t & 63) == 0) { rs[wv] = s; rc[wv] = cnt; }
    __syncthreads();
    if (t == 0) {
        float S = rs[0] + rs[1] + rs[2] + rs[3];
        float C = (float)(rc[0] + rc[1] + rc[2] + rc[3]);
        atomicAdd(out, (S / C) * (1.0f / 16.0f));
    }
}

extern "C" void kernel_launch(void* const* d_in, const int* in_sizes, int n_in,
                              void* d_out, int out_size, void* d_ws, size_t ws_size,
                              hipStream_t stream) {
    const float* x    = (const float*)d_in[0];
    const float* y    = (const float*)d_in[1];
    const int*   mask = (const int*)d_in[2];

    float* rowpart = (float*)d_ws;                        // B*NCB*2*N = 4 MB
    float* colpart = rowpart + (size_t)B * NCB * 2 * N;   // B*NSB*N   = 2 MB

    chamfer_mfma<<<dim3(B * NCB * NSB), 256, 0, stream>>>(
        x, y, mask, rowpart, colpart, (float*)d_out);
    finalize_kernel<<<dim3(64), 256, 0, stream>>>(
        mask, rowpart, colpart, (float*)d_out);
}

// Round 20
// 85.020 us; speedup vs baseline: 1.5418x; 1.0313x over previous
//
#include <hip/hip_runtime.h>

typedef short bf16x8 __attribute__((ext_vector_type(8)));
typedef float f32x16 __attribute__((ext_vector_type(16)));

#define BIG_F 1e10f
constexpr int B = 16;
constexpr int N = 4096;
constexpr int COLS = 512;           // y-cols per block
constexpr int NCB = N / COLS;       // 8 col-blocks
constexpr int PASSES = 2;           // 256-row passes per block (2 streams each)
constexpr int SUBROWS = 512;        // rows per block
constexpr int NSB = N / SUBROWS;    // 8 row-superblocks

// truncating bf16 hi/lo split: v ~= hi + lo
__device__ __forceinline__ void split(float v, unsigned& h, unsigned& l) {
    unsigned hb = __float_as_uint(v) & 0xFFFF0000u;
    h = hb >> 16;
    float r = v - __uint_as_float(hb);
    l = __float_as_uint(r) >> 16;
}

__device__ __forceinline__ float min3f(float a, float b, float c) {
    return fminf(fminf(a, b), c);   // fuses to v_min3_f32
}

__device__ __forceinline__ float vmin16(f32x16 C) {
    float u0 = min3f(C[0], C[1], C[2]);
    float u1 = min3f(C[3], C[4], C[5]);
    float u2 = min3f(C[6], C[7], C[8]);
    float u3 = min3f(C[9], C[10], C[11]);
    float u4 = min3f(C[12], C[13], C[14]);
    return min3f(min3f(u0, u1, u2), fminf(u3, u4), C[15]);
}

__device__ __forceinline__ float4 min4(float4 a, float4 b) {
    return make_float4(fminf(a.x, b.x), fminf(a.y, b.y),
                       fminf(a.z, b.z), fminf(a.w, b.w));
}

// VALU-pipe cross-lane min via DPP (no ds-op). Validated exact (R8-R19).
#define DPP_MIN(v, ctrl)                                                      \
    v = fminf(v, __int_as_float(__builtin_amdgcn_update_dpp(                  \
            __float_as_int(v), __float_as_int(v), (ctrl), 0xF, 0xF, false)))

// FINAL (session-best, R13 = 86.0us): ILP-2 fused chamfer.
// P[n,m] = xx[n] + yy[m] - 2 x_n . y_m (+BIG masked) via mfma_f32_32x32x16_bf16
// (all 16 K-slots used via hi/lo bf16 split — bit-exact vs fp32 reference):
//   A_k(n) = [ah0..2, ah0..2, al0..2, al0..2, xxh, xxl, 1, 1]  (ah+al = -2x)
//   B_k(m) = [yh0..2, yl0..2, yh0..2, yl0..2, 1, 1, qh, ql]    (qh+ql = yy)
// Each wave runs TWO 32-row streams against shared B fragments; row-mins
// reduced on the VALU pipe via DPP; col-mins accumulated in thread-owned LDS
// slots (race-free rmw); 2 barriers per block; grid 1024 @ (256,3).
// Register-budget map from 19 rounds: <=64 budget -> AGPR-ized accum (4x VALU,
// R17); 128 + fat body -> scratch collapse (R3/R8); ~102-170 + this body ->
// clean. Occupancy 3/4/5 w/SIMD measured flat (86.0/86.9/87.7) — this is the
// measured minimum configuration.
__global__ __launch_bounds__(256, 3) void chamfer_mfma(
    const float* __restrict__ x, const float* __restrict__ y,
    const int* __restrict__ mask,
    float* __restrict__ rowpart,   // [B][NCB][2][N] row-min partials (sset slabs)
    float* __restrict__ colpart,   // [B][NSB][N]    col-min partials (512 rows)
    float* __restrict__ out)
{
    const int blk = blockIdx.x;     // 0..1023
    const int b   = blk >> 6;
    const int cb  = (blk >> 3) & 7;
    const int sub = blk & 7;
    const int t   = threadIdx.x;

    __shared__ __align__(16) unsigned short Bpack[2][COLS][8];  // 16 KB
    __shared__ float colbuf[8][COLS];                           // 16 KB

    if (blk == 0 && t == 0) out[0] = 0.0f;   // finalize is the next dispatch

    const float* xb = x + (size_t)b * 3 * N;
    const float* yb = y + (size_t)b * 3 * N;
    const int*   mb = mask + b * N;

    // ---- pack this block's 512-col B slice (2 points/thread) ----
#pragma unroll
    for (int i = 0; i < 2; ++i) {
        int c = t + i * 256;
        int m = cb * COLS + c;
        float y0 = yb[m], y1 = yb[N + m], y2 = yb[2 * N + m];
        float madd = mb[m] ? 0.0f : BIG_F;
        float yy = fmaf(y2, y2, fmaf(y1, y1, y0 * y0)) + madd;
        unsigned h0, l0, h1, l1, h2, l2, qh, ql;
        split(y0, h0, l0);
        split(y1, h1, l1);
        split(y2, h2, l2);
        split(yy, qh, ql);
        unsigned u0 = h0 | (h1 << 16);
        unsigned u1 = h2 | (l0 << 16);
        unsigned u2 = l1 | (l2 << 16);
        uint4 w0 = { u0, u1, u2, u0 };
        uint4 w1 = { u1, u2, 0x3F803F80u, qh | (ql << 16) };
        *(uint4*)&Bpack[0][c][0] = w0;
        *(uint4*)&Bpack[1][c][0] = w1;
    }

    const int w    = t >> 6;    // wave 0..3
    const int L    = t & 63;
    const int half = L >> 5;    // k-half 0/1
    const int lc   = L & 31;

    __syncthreads();

    const unsigned short* Bb = &Bpack[half][lc][0];  // +p*512 shorts = col p*64+lc
    float* cacc0 = &colbuf[w * 2 + half][lc];        // thread-owned col-min slots

    const f32x16 z16 = {0.f,0.f,0.f,0.f,0.f,0.f,0.f,0.f,
                        0.f,0.f,0.f,0.f,0.f,0.f,0.f,0.f};

    auto buildA = [&](int n) -> bf16x8 {
        float x0 = xb[n], x1 = xb[N + n], x2 = xb[2 * N + n];
        float madd = mb[n] ? 0.0f : BIG_F;
        float xx = fmaf(x2, x2, fmaf(x1, x1, x0 * x0)) + madd;
        unsigned h0, l0, h1, l1, h2, l2, xh, xl;
        split(-2.0f * x0, h0, l0);
        split(-2.0f * x1, h1, l1);
        split(-2.0f * x2, h2, l2);
        split(xx, xh, xl);
        uint4 wa;
        wa.x = half ? (l2 | (l0 << 16)) : (h0 | (h1 << 16));
        wa.y = half ? (l1 | (l2 << 16)) : (h2 | (h0 << 16));
        wa.z = half ? (xh | (xl << 16)) : (h1 | (h2 << 16));
        wa.w = half ? 0x3F803F80u       : (l0 | (l1 << 16));
        return *(bf16x8*)&wa;
    };

#pragma unroll 1
    for (int pass = 0; pass < PASSES; ++pass) {
        const int rowbase = sub * SUBROWS + pass * 256;
        // two 32-row streams per wave: rows rowbase+w*32 (A), +128 (B)
        bf16x8 afrA = buildA(rowbase + w * 32 + lc);
        bf16x8 afrB = buildA(rowbase + 128 + w * 32 + lc);

        float rmA[16], rmB[16];
#pragma unroll
        for (int r = 0; r < 16; ++r) { rmA[r] = 1e30f; rmB[r] = 1e30f; }

#pragma unroll 1
        for (int p = 0; p < 8; ++p) {          // 8 col-pairs of 32 = 512 cols
            bf16x8 bf0 = *(const bf16x8*)(Bb + p * 512);
            bf16x8 bf1 = *(const bf16x8*)(Bb + p * 512 + 256);
            f32x16 C0a = __builtin_amdgcn_mfma_f32_32x32x16_bf16(afrA, bf0, z16, 0, 0, 0);
            f32x16 C0b = __builtin_amdgcn_mfma_f32_32x32x16_bf16(afrB, bf0, z16, 0, 0, 0);
            f32x16 C1a = __builtin_amdgcn_mfma_f32_32x32x16_bf16(afrA, bf1, z16, 0, 0, 0);
            f32x16 C1b = __builtin_amdgcn_mfma_f32_32x32x16_bf16(afrB, bf1, z16, 0, 0, 0);
            // C[r]: row = base + (r&3)+8*(r>>2)+4*half, col = p*64(+32)+lc
#pragma unroll
            for (int r = 0; r < 16; ++r) {
                rmA[r] = min3f(rmA[r], C0a[r], C1a[r]);
                rmB[r] = min3f(rmB[r], C0b[r], C1b[r]);
            }
            // col partials: min over both streams' 16-row halves, rmw LDS
            float v0 = fminf(vmin16(C0a), vmin16(C0b));
            float v1 = fminf(vmin16(C1a), vmin16(C1b));
            if (pass == 0) {
                cacc0[p * 64]      = v0;
                cacc0[p * 64 + 32] = v1;
            } else {
                cacc0[p * 64]      = fminf(cacc0[p * 64],      v0);
                cacc0[p * 64 + 32] = fminf(cacc0[p * 64 + 32], v1);
            }
        }

        // ---- row-min over each 16-lane group, entirely on the VALU pipe ----
#pragma unroll
        for (int r = 0; r < 16; ++r) {
            DPP_MIN(rmA[r], 0xB1);   DPP_MIN(rmB[r], 0xB1);   // quad xor1
            DPP_MIN(rmA[r], 0x4E);   DPP_MIN(rmB[r], 0x4E);   // quad xor2
            DPP_MIN(rmA[r], 0x124);  DPP_MIN(rmB[r], 0x124);  // row_ror:4
            DPP_MIN(rmA[r], 0x128);  DPP_MIN(rmB[r], 0x128);  // row_ror:8
        }
        if ((lc & 15) == 0) {        // lanes 0,16,32,48: (half, col-subset)
            int sset = lc >> 4;
            float* rpA = rowpart + (((size_t)(b * NCB + cb)) * 2 + sset) * N
                       + rowbase + w * 32 + half * 4;
            float* rpB = rpA + 128;
            *(float4*)(rpA +  0) = make_float4(rmA[0],  rmA[1],  rmA[2],  rmA[3]);
            *(float4*)(rpA +  8) = make_float4(rmA[4],  rmA[5],  rmA[6],  rmA[7]);
            *(float4*)(rpA + 16) = make_float4(rmA[8],  rmA[9],  rmA[10], rmA[11]);
            *(float4*)(rpA + 24) = make_float4(rmA[12], rmA[13], rmA[14], rmA[15]);
            *(float4*)(rpB +  0) = make_float4(rmB[0],  rmB[1],  rmB[2],  rmB[3]);
            *(float4*)(rpB +  8) = make_float4(rmB[4],  rmB[5],  rmB[6],  rmB[7]);
            *(float4*)(rpB + 16) = make_float4(rmB[8],  rmB[9],  rmB[10], rmB[11]);
            *(float4*)(rpB + 24) = make_float4(rmB[12], rmB[13], rmB[14], rmB[15]);
        }
    }

    __syncthreads();
    if (t < 128) {                   // combine 8 (wave,half) slabs, float4-wide
        const float4* cb4 = (const float4*)&colbuf[0][0];
        float4 v = cb4[t];
#pragma unroll
        for (int s = 1; s < 8; ++s) v = min4(v, cb4[s * 128 + t]);
        *(float4*)(colpart + ((size_t)b * NSB + sub) * N + cb * COLS + t * 4) = v;
    }
}

__global__ __launch_bounds__(256) void finalize_kernel(
    const int* __restrict__ mask,
    const float* __restrict__ rowpart, const float* __restrict__ colpart,
    float* __restrict__ out)
{
    const int b = blockIdx.x & 15;
    const int q = blockIdx.x >> 4;   // quarter 0..3
    const int t = threadIdx.x;
    const int* mrow = mask + b * N;

    int cnt = 0;
    for (int i = t; i < N / 4; i += 256) {
        int4 mk = ((const int4*)mrow)[i];
        cnt += mk.x + mk.y + mk.z + mk.w;
    }

    const int p0 = q * 1024 + t * 4;
    const float* cp = colpart + (size_t)b * NSB * N + p0;      // 8 slabs
    const float* rp = rowpart + (size_t)b * NCB * 2 * N + p0;  // 16 slabs

    float4 mn = *(const float4*)cp;
    float4 rn = *(const float4*)rp;
#pragma unroll 8
    for (int pb = 1; pb < NCB * 2; ++pb) {
        rn = min4(rn, *(const float4*)(rp + (size_t)pb * N));
        if (pb < NSB)
            mn = min4(mn, *(const float4*)(cp + (size_t)pb * N));
    }
    int4 mk = *(const int4*)(mrow + p0);
    float s = (mk.x ? (mn.x + rn.x) : 0.f) + (mk.y ? (mn.y + rn.y) : 0.f)
            + (mk.z ? (mn.z + rn.z) : 0.f) + (mk.w ? (mn.w + rn.w) : 0.f);

    for (int off = 32; off > 0; off >>= 1) {
        s   += __shfl_down(s, off);
        cnt += __shfl_down(cnt, off);
    }
    __shared__ float rs[4];
    __shared__ int   rc[4];
    const int wv = t >> 6;
    if ((t & 63) == 0) { rs[wv] = s; rc[wv] = cnt; }
    __syncthreads();
    if (t == 0) {
        float S = rs[0] + rs[1] + rs[2] + rs[3];
        float C = (float)(rc[0] + rc[1] + rc[2] + rc[3]);
        atomicAdd(out, (S / C) * (1.0f / 16.0f));
    }
}

extern "C" void kernel_launch(void* const* d_in, const int* in_sizes, int n_in,
                              void* d_out, int out_size, void* d_ws, size_t ws_size,
                              hipStream_t stream) {
    const float* x    = (const float*)d_in[0];
    const float* y    = (const float*)d_in[1];
    const int*   mask = (const int*)d_in[2];

    float* rowpart = (float*)d_ws;                        // B*NCB*2*N = 4 MB
    float* colpart = rowpart + (size_t)B * NCB * 2 * N;   // B*NSB*N   = 2 MB

    chamfer_mfma<<<dim3(B * NCB * NSB), 256, 0, stream>>>(
        x, y, mask, rowpart, colpart, (float*)d_out);
    finalize_kernel<<<dim3(64), 256, 0, stream>>>(
        mask, rowpart, colpart, (float*)d_out);
}